// Round 11
// baseline (124.530 us; speedup 1.0000x reference)
//
#include <hip/hip_runtime.h>

// LSTM_13451837571407 — R11: R10 (NTILES=3 + cvt_pkrtz) with compile fix.
// R10 failed to compile: __builtin_amdgcn_cvt_pkrtz returns __fp16x2, needs
// bit_cast to our _Float16x2. Everything else identical to R10's plan.
//
// R9 postmortem: 1024-thr blocks -> residency thread-capped (2 blocks/CU);
// VALUBusy 67%, ~45µs dependency stall vs 69µs issue floor. Adding per-wave
// ILP is free while VGPR<=64 (32-waves/CU cliff). 3 tiles/wave = 6 activation
// chains; per-layer weight/bias LDS reads amortized 3 ways.
//
// Datapath (verified; absmax pinned at 2.441e-4 output-quant floor R2-R9):
//   layer 0: gates = x@W_ih0^T + (b_ih0+b_hh0)        (h=c=0, K padded 14->16)
//   layer l>=1: gates = h@(W_ih[l-1]+W_hh[l])^T + bc  (input==hidden quirk)
//   rows i,f,o scaled by -log2e (sigmoid=1/(1+exp2(y)));
//   rows g scaled by 2log2e (tanh=(exp2(y)-1)/(exp2(y)+1)).
//   W = fp16_hi + fp16_lo (22 bits), h = fp16; one v_mfma_f32_16x16x32_f16
//   with A=[Wh|Wl], B=[hf|hf] per gate-quadrant (K32 = two stacked K16 frags,
//   proven R7). Lane's D rows == its next-layer B k-slots (zero shuffles).

typedef _Float16 f16x8 __attribute__((ext_vector_type(8)));
typedef _Float16 f16x2 __attribute__((ext_vector_type(2)));
typedef float f32x4 __attribute__((ext_vector_type(4)));
typedef float f32x2 __attribute__((ext_vector_type(2)));

#if __has_builtin(__builtin_amdgcn_mfma_f32_16x16x32_f16)
__device__ __forceinline__ f32x4 mfma32h(f16x8 a, f16x8 b, f32x4 c) {
    return __builtin_amdgcn_mfma_f32_16x16x32_f16(a, b, c, 0, 0, 0);
}
#else
__device__ __forceinline__ f32x4 mfma32h(f16x8 a, f16x8 b, f32x4 c) {
    asm volatile("v_mfma_f32_16x16x32_f16 %0, %1, %2, %0\n\ts_nop 7\n\ts_nop 7"
                 : "+v"(c) : "v"(a), "v"(b));
    return c;
}
#endif

#define NLOG2E  (-1.4426950408889634f)
#define G2LOG2E (2.8853900817779268f)
#define THREADS 1024
#define WAVES_PB (THREADS / 64)
#define NBLOCKS 512
#define NTILES 3

// LSTM nonlinearity on a pair of units (packed f32x2); rows pre-scaled.
__device__ __forceinline__ void act2(f32x2 yi, f32x2 yf, f32x2 yg, f32x2 yo,
                                     f32x2& c, f32x2& h) {
    f32x2 Ei, Ef, Eg, Eo;
    Ei[0] = __builtin_amdgcn_exp2f(yi[0]); Ei[1] = __builtin_amdgcn_exp2f(yi[1]);
    Ef[0] = __builtin_amdgcn_exp2f(yf[0]); Ef[1] = __builtin_amdgcn_exp2f(yf[1]);
    Eg[0] = __builtin_amdgcn_exp2f(yg[0]); Eg[1] = __builtin_amdgcn_exp2f(yg[1]);
    Eo[0] = __builtin_amdgcn_exp2f(yo[0]); Eo[1] = __builtin_amdgcn_exp2f(yo[1]);
    const f32x2 one = {1.f, 1.f};
    const f32x2 Di = Ei + one, Df = Ef + one, Do = Eo + one;
    const f32x2 P = __builtin_elementwise_fma(Di, Eg, Di);           // Di*(Eg+1)
    const f32x2 num = __builtin_elementwise_fma(
        Eg, Df, __builtin_elementwise_fma(c, P, -Df));               // (Eg-1)Df+cP
    const f32x2 DfP = Df * P;
    f32x2 R1;
    R1[0] = __builtin_amdgcn_rcpf(DfP[0]); R1[1] = __builtin_amdgcn_rcpf(DfP[1]);
    c = num * R1;
    const f32x2 cg = c * (f32x2){G2LOG2E, G2LOG2E};
    f32x2 Ec;
    Ec[0] = __builtin_amdgcn_exp2f(cg[0]); Ec[1] = __builtin_amdgcn_exp2f(cg[1]);
    const f32x2 Q = __builtin_elementwise_fma(Do, Ec, Do);           // Do*(Ec+1)
    f32x2 R2;
    R2[0] = __builtin_amdgcn_rcpf(Q[0]); R2[1] = __builtin_amdgcn_rcpf(Q[1]);
    h = __builtin_elementwise_fma(Ec, R2, -R2);                      // (Ec-1)/Q
}

#define LOP(v) __builtin_shufflevector(v, v, 0, 1)
#define HIP2(v) __builtin_shufflevector(v, v, 2, 3)

// duplicate-quad fp16 B fragment via packed RTZ converts: [h0..h3 | h0..h3]
__device__ __forceinline__ f16x8 make_bfrag(f32x2 ha, f32x2 hb) {
    const f16x2 p0 = __builtin_bit_cast(f16x2, __builtin_amdgcn_cvt_pkrtz(ha[0], ha[1]));
    const f16x2 p1 = __builtin_bit_cast(f16x2, __builtin_amdgcn_cvt_pkrtz(hb[0], hb[1]));
    return (f16x8){p0[0], p0[1], p1[0], p1[1], p0[0], p0[1], p1[0], p1[1]};
}

__global__ __launch_bounds__(THREADS, 2) void lstm_mfma_kernel(
    const float* __restrict__ x,      // [B][14]
    const float* __restrict__ W_ih0,  // [64][14]
    const float* __restrict__ W_ih,   // [7][64][16]
    const float* __restrict__ W_hh,   // [8][64][16]
    const float* __restrict__ b_ih,   // [8][64]
    const float* __restrict__ b_hh,   // [8][64]
    const float* __restrict__ fc_w,   // [16]
    const float* __restrict__ fc_b,   // [1]
    float* __restrict__ out,          // [B]
    int nB)
{
    // fragment-major: sWF[(l*4+t)*64 + lane] = 8 halfs [Wh0..3 | Wl0..3]
    __shared__ __align__(16) short sWF[8 * 4 * 64 * 8];  // 32 KB
    __shared__ __align__(16) float sB[8 * 64];
    __shared__ __align__(16) float sFC[20];

    const int tid = threadIdx.x;

    for (int slot = tid; slot < 2048; slot += THREADS) {
        const int l = slot >> 8;
        const int t = (slot >> 6) & 3;
        const int ln = slot & 63;
        const int row = t * 16 + (ln & 15);
        const int k0 = (ln >> 4) * 4;
        const float scale = (t == 2) ? G2LOG2E : NLOG2E;
        short frag[8];
        #pragma unroll
        for (int j = 0; j < 4; ++j) {
            const int k = k0 + j;
            float w;
            if (l == 0) w = (k < 14) ? W_ih0[row * 14 + k] : 0.0f;
            else        w = W_ih[(l - 1) * 1024 + row * 16 + k]
                          + W_hh[l * 1024 + row * 16 + k];
            w *= scale;
            const _Float16 wh = (_Float16)w;            // RNE fp16 hi
            const float wres = w - (float)wh;
            const _Float16 wl = (_Float16)wres;         // fp16 lo (22 bits total)
            frag[j]     = __builtin_bit_cast(short, wh);
            frag[4 + j] = __builtin_bit_cast(short, wl);
        }
        *(short4*)(sWF + slot * 8)     = make_short4(frag[0], frag[1], frag[2], frag[3]);
        *(short4*)(sWF + slot * 8 + 4) = make_short4(frag[4], frag[5], frag[6], frag[7]);
    }
    for (int idx = tid; idx < 512; idx += THREADS) {
        const int row = idx & 63;
        const float scale = ((row >> 4) == 2) ? G2LOG2E : NLOG2E;
        sB[idx] = (b_ih[idx] + b_hh[idx]) * scale;
    }
    if (tid < 16) sFC[tid] = fc_w[tid];
    if (tid == 16) sFC[16] = fc_b[0];
    __syncthreads();

    const int lane = tid & 63;
    const int wv = tid >> 6;
    const int bcol = lane & 15;   // batch within tile
    const int hi = lane >> 4;     // k-quad / D-row group

    const int n_grp = (nB + (16 * NTILES - 1)) / (16 * NTILES);
    const int waves_total = NBLOCKS * WAVES_PB;
    const int iters = (n_grp + waves_total - 1) / waves_total;
    const int gw = blockIdx.x * WAVES_PB + wv;

    const short* wbase = sWF + (lane << 3);
    const float* bbase = sB + hi * 4;

    const f32x4 fw4 = *(const f32x4*)(sFC + hi * 4);
    const f32x2 fwa = LOP(fw4), fwb = HIP2(fw4);
    const float fb = sFC[16];

    for (int it = 0; it < iters; ++it) {
        const int grp = gw * iters + it;
        if (grp >= n_grp) break;

        int bidx[NTILES];
        f32x2 ha[NTILES], hb[NTILES];
        f16x8 Bf[NTILES];
        f32x2 ca[NTILES], cb[NTILES];

        #pragma unroll
        for (int m = 0; m < NTILES; ++m) {
            const int b = grp * (16 * NTILES) + m * 16 + bcol;
            bidx[m] = b;
            const int bc = b < nB ? b : nB - 1;
            const float* xr = x + bc * 14 + hi * 4;
            const float2 p = *(const float2*)xr;
            ha[m][0] = p.x; ha[m][1] = p.y;
            if (hi < 3) {
                const float2 q = *(const float2*)(xr + 2);
                hb[m][0] = q.x; hb[m][1] = q.y;
            } else { hb[m] = (f32x2){0.f, 0.f}; }
            Bf[m] = make_bfrag(ha[m], hb[m]);
            ca[m] = (f32x2){0.f, 0.f};
            cb[m] = (f32x2){0.f, 0.f};
        }

        #pragma unroll
        for (int l = 0; l < 8; ++l) {
            // shared per-layer loads: 4 weight frags [Wh|Wl] + 4 bias quads
            f16x8 fr[4];
            f32x4 bias[4];
            #pragma unroll
            for (int t = 0; t < 4; ++t) {
                fr[t] = *(const f16x8*)(wbase + ((l * 4 + t) << 9));
                bias[t] = *(const f32x4*)(bbase + l * 64 + t * 16);
            }
            #pragma unroll
            for (int m = 0; m < NTILES; ++m) {
                f32x4 a[4];
                #pragma unroll
                for (int t = 0; t < 4; ++t) {
                    // (Wh+Wl)·hf in one K32 MFMA (two stacked K16 fragments)
                    a[t] = mfma32h(fr[t], Bf[m], bias[t]);
                }
                act2(LOP(a[0]), LOP(a[1]), LOP(a[2]), LOP(a[3]), ca[m], ha[m]);
                act2(HIP2(a[0]), HIP2(a[1]), HIP2(a[2]), HIP2(a[3]), cb[m], hb[m]);
                Bf[m] = make_bfrag(ha[m], hb[m]);
            }
        }

        // ---- FC head: dot(h, fc_w), reduce across 4 hi-lane groups ----
        #pragma unroll
        for (int m = 0; m < NTILES; ++m) {
            f32x2 s = ha[m] * fwa;
            s = __builtin_elementwise_fma(hb[m], fwb, s);
            float p = s[0] + s[1];
            p += __shfl_xor(p, 16, 64);
            p += __shfl_xor(p, 32, 64);
            if (hi == 0 && bidx[m] < nB) out[bidx[m]] = p + fb;
        }
    }
}

extern "C" void kernel_launch(void* const* d_in, const int* in_sizes, int n_in,
                              void* d_out, int out_size, void* d_ws, size_t ws_size,
                              hipStream_t stream) {
    const float* x     = (const float*)d_in[0];
    const float* W_ih0 = (const float*)d_in[1];
    const float* W_ih  = (const float*)d_in[2];
    const float* W_hh  = (const float*)d_in[3];
    const float* b_ih  = (const float*)d_in[4];
    const float* b_hh  = (const float*)d_in[5];
    const float* fc_w  = (const float*)d_in[6];
    const float* fc_b  = (const float*)d_in[7];
    float* out = (float*)d_out;

    const int B = in_sizes[0] / 14;
    lstm_mfma_kernel<<<NBLOCKS, THREADS, 0, stream>>>(
        x, W_ih0, W_ih, W_hh, b_ih, b_hh, fc_w, fc_b, out, B);
}

// Round 12
// 115.176 us; speedup vs baseline: 1.0812x; 1.0812x over previous
//
#include <hip/hip_runtime.h>

// LSTM_13451837571407 — R12: R9 datapath + hoisted 8-MFMA window + x prefetch.
// R11 postmortem: NTILES=3 regressed (work imbalance: 21846 groups % 3-iter
// mapping idles 11% of waves; bigger live state scheduled worse). Reverted to
// NTILES=2/1024thr (exact 4-iter division). R12 changes vs R9:
//  (1) both tiles' 4 MFMAs issued together at top of layer body (8-deep
//      independent MFMA window before the ~110cy trans chains),
//  (2) next group's x loaded into regs during current group's 8 layers
//      (hides ~500-900cy HBM latency),
//  (3) __launch_bounds__(1024,8) pins VGPR<=64 (8 waves/SIMD cliff).
//
// Datapath (verified; absmax pinned at 2.441e-4 output-quant floor R2-R11):
//   layer 0: gates = x@W_ih0^T + (b_ih0+b_hh0)        (h=c=0, K padded 14->16)
//   layer l>=1: gates = h@(W_ih[l-1]+W_hh[l])^T + bc  (input==hidden quirk)
//   rows i,f,o scaled by -log2e (sigmoid=1/(1+exp2(y)));
//   rows g scaled by 2log2e (tanh=(exp2(y)-1)/(exp2(y)+1)).
//   W = fp16_hi + fp16_lo (22 bits), h = fp16 (cvt_pkrtz); one
//   v_mfma_f32_16x16x32_f16 with A=[Wh|Wl], B=[hf|hf] per gate-quadrant
//   (K32 = two stacked K16 frags, proven R7). Lane's D rows == its next-layer
//   B k-slots (zero cross-lane traffic).

typedef _Float16 f16x8 __attribute__((ext_vector_type(8)));
typedef _Float16 f16x2 __attribute__((ext_vector_type(2)));
typedef float f32x4 __attribute__((ext_vector_type(4)));
typedef float f32x2 __attribute__((ext_vector_type(2)));

#if __has_builtin(__builtin_amdgcn_mfma_f32_16x16x32_f16)
__device__ __forceinline__ f32x4 mfma32h(f16x8 a, f16x8 b, f32x4 c) {
    return __builtin_amdgcn_mfma_f32_16x16x32_f16(a, b, c, 0, 0, 0);
}
#else
__device__ __forceinline__ f32x4 mfma32h(f16x8 a, f16x8 b, f32x4 c) {
    asm volatile("v_mfma_f32_16x16x32_f16 %0, %1, %2, %0\n\ts_nop 7\n\ts_nop 7"
                 : "+v"(c) : "v"(a), "v"(b));
    return c;
}
#endif

#define NLOG2E  (-1.4426950408889634f)
#define G2LOG2E (2.8853900817779268f)
#define THREADS 1024
#define WAVES_PB (THREADS / 64)
#define NBLOCKS 512
#define NTILES 2

// LSTM nonlinearity on a pair of units (packed f32x2); rows pre-scaled.
__device__ __forceinline__ void act2(f32x2 yi, f32x2 yf, f32x2 yg, f32x2 yo,
                                     f32x2& c, f32x2& h) {
    f32x2 Ei, Ef, Eg, Eo;
    Ei[0] = __builtin_amdgcn_exp2f(yi[0]); Ei[1] = __builtin_amdgcn_exp2f(yi[1]);
    Ef[0] = __builtin_amdgcn_exp2f(yf[0]); Ef[1] = __builtin_amdgcn_exp2f(yf[1]);
    Eg[0] = __builtin_amdgcn_exp2f(yg[0]); Eg[1] = __builtin_amdgcn_exp2f(yg[1]);
    Eo[0] = __builtin_amdgcn_exp2f(yo[0]); Eo[1] = __builtin_amdgcn_exp2f(yo[1]);
    const f32x2 one = {1.f, 1.f};
    const f32x2 Di = Ei + one, Df = Ef + one, Do = Eo + one;
    const f32x2 P = __builtin_elementwise_fma(Di, Eg, Di);           // Di*(Eg+1)
    const f32x2 num = __builtin_elementwise_fma(
        Eg, Df, __builtin_elementwise_fma(c, P, -Df));               // (Eg-1)Df+cP
    const f32x2 DfP = Df * P;
    f32x2 R1;
    R1[0] = __builtin_amdgcn_rcpf(DfP[0]); R1[1] = __builtin_amdgcn_rcpf(DfP[1]);
    c = num * R1;
    const f32x2 cg = c * (f32x2){G2LOG2E, G2LOG2E};
    f32x2 Ec;
    Ec[0] = __builtin_amdgcn_exp2f(cg[0]); Ec[1] = __builtin_amdgcn_exp2f(cg[1]);
    const f32x2 Q = __builtin_elementwise_fma(Do, Ec, Do);           // Do*(Ec+1)
    f32x2 R2;
    R2[0] = __builtin_amdgcn_rcpf(Q[0]); R2[1] = __builtin_amdgcn_rcpf(Q[1]);
    h = __builtin_elementwise_fma(Ec, R2, -R2);                      // (Ec-1)/Q
}

#define LOP(v) __builtin_shufflevector(v, v, 0, 1)
#define HIP2(v) __builtin_shufflevector(v, v, 2, 3)

// duplicate-quad fp16 B fragment via packed RTZ converts: [h0..h3 | h0..h3]
__device__ __forceinline__ f16x8 make_bfrag(f32x2 ha, f32x2 hb) {
    const f16x2 p0 = __builtin_bit_cast(f16x2, __builtin_amdgcn_cvt_pkrtz(ha[0], ha[1]));
    const f16x2 p1 = __builtin_bit_cast(f16x2, __builtin_amdgcn_cvt_pkrtz(hb[0], hb[1]));
    return (f16x8){p0[0], p0[1], p1[0], p1[1], p0[0], p0[1], p1[0], p1[1]};
}

__global__ __launch_bounds__(THREADS, 8) void lstm_mfma_kernel(
    const float* __restrict__ x,      // [B][14]
    const float* __restrict__ W_ih0,  // [64][14]
    const float* __restrict__ W_ih,   // [7][64][16]
    const float* __restrict__ W_hh,   // [8][64][16]
    const float* __restrict__ b_ih,   // [8][64]
    const float* __restrict__ b_hh,   // [8][64]
    const float* __restrict__ fc_w,   // [16]
    const float* __restrict__ fc_b,   // [1]
    float* __restrict__ out,          // [B]
    int nB)
{
    // fragment-major: sWF[(l*4+t)*64 + lane] = 8 halfs [Wh0..3 | Wl0..3]
    __shared__ __align__(16) short sWF[8 * 4 * 64 * 8];  // 32 KB
    __shared__ __align__(16) float sB[8 * 64];
    __shared__ __align__(16) float sFC[20];

    const int tid = threadIdx.x;

    for (int slot = tid; slot < 2048; slot += THREADS) {
        const int l = slot >> 8;
        const int t = (slot >> 6) & 3;
        const int ln = slot & 63;
        const int row = t * 16 + (ln & 15);
        const int k0 = (ln >> 4) * 4;
        const float scale = (t == 2) ? G2LOG2E : NLOG2E;
        short frag[8];
        #pragma unroll
        for (int j = 0; j < 4; ++j) {
            const int k = k0 + j;
            float w;
            if (l == 0) w = (k < 14) ? W_ih0[row * 14 + k] : 0.0f;
            else        w = W_ih[(l - 1) * 1024 + row * 16 + k]
                          + W_hh[l * 1024 + row * 16 + k];
            w *= scale;
            const _Float16 wh = (_Float16)w;            // RNE fp16 hi
            const float wres = w - (float)wh;
            const _Float16 wl = (_Float16)wres;         // fp16 lo (22 bits total)
            frag[j]     = __builtin_bit_cast(short, wh);
            frag[4 + j] = __builtin_bit_cast(short, wl);
        }
        *(short4*)(sWF + slot * 8)     = make_short4(frag[0], frag[1], frag[2], frag[3]);
        *(short4*)(sWF + slot * 8 + 4) = make_short4(frag[4], frag[5], frag[6], frag[7]);
    }
    for (int idx = tid; idx < 512; idx += THREADS) {
        const int row = idx & 63;
        const float scale = ((row >> 4) == 2) ? G2LOG2E : NLOG2E;
        sB[idx] = (b_ih[idx] + b_hh[idx]) * scale;
    }
    if (tid < 16) sFC[tid] = fc_w[tid];
    if (tid == 16) sFC[16] = fc_b[0];
    __syncthreads();

    const int lane = tid & 63;
    const int wv = tid >> 6;
    const int bcol = lane & 15;   // batch within tile
    const int hi = lane >> 4;     // k-quad / D-row group

    const int n_grp = (nB + (16 * NTILES - 1)) / (16 * NTILES);
    const int waves_total = NBLOCKS * WAVES_PB;
    const int iters = (n_grp + waves_total - 1) / waves_total;
    const int gw = blockIdx.x * WAVES_PB + wv;
    const int grp_base = gw * iters;

    const short* wbase = sWF + (lane << 3);
    const float* bbase = sB + hi * 4;

    const f32x4 fw4 = *(const f32x4*)(sFC + hi * 4);
    const f32x2 fwa = LOP(fw4), fwb = HIP2(fw4);
    const float fb = sFC[16];

    // ---- register double-buffer for x ----
    int pf_b[NTILES];
    float2 pf_a[NTILES], pf_q[NTILES];
    auto prefetch = [&](int grp) {
        #pragma unroll
        for (int m = 0; m < NTILES; ++m) {
            const int b = grp * (16 * NTILES) + m * 16 + bcol;
            pf_b[m] = b;
            const int bc = b < nB ? b : nB - 1;
            const float* xr = x + bc * 14 + hi * 4;
            pf_a[m] = *(const float2*)xr;
            pf_q[m] = (hi < 3) ? *(const float2*)(xr + 2) : make_float2(0.f, 0.f);
        }
    };

    if (grp_base < n_grp) prefetch(grp_base);

    for (int it = 0; it < iters; ++it) {
        const int grp = grp_base + it;
        if (grp >= n_grp) break;

        // consume prefetched x
        int bidx[NTILES];
        f32x2 ha[NTILES], hb[NTILES];
        f16x8 Bf[NTILES];
        f32x2 ca[NTILES], cb[NTILES];
        #pragma unroll
        for (int m = 0; m < NTILES; ++m) {
            bidx[m] = pf_b[m];
            ha[m][0] = pf_a[m].x; ha[m][1] = pf_a[m].y;
            hb[m][0] = pf_q[m].x; hb[m][1] = pf_q[m].y;
            Bf[m] = make_bfrag(ha[m], hb[m]);
            ca[m] = (f32x2){0.f, 0.f};
            cb[m] = (f32x2){0.f, 0.f};
        }
        // issue next group's x loads; latency hides under 8 layers
        if (it + 1 < iters && grp + 1 < n_grp) prefetch(grp + 1);

        #pragma unroll
        for (int l = 0; l < 8; ++l) {
            // 8 independent MFMAs issued together (both tiles) — wide window
            f32x4 a0[4], a1[4];
            #pragma unroll
            for (int t = 0; t < 4; ++t) {
                const f16x8 fr = *(const f16x8*)(wbase + ((l * 4 + t) << 9));
                const f32x4 bias = *(const f32x4*)(bbase + l * 64 + t * 16);
                a0[t] = mfma32h(fr, Bf[0], bias);
                a1[t] = mfma32h(fr, Bf[1], bias);
            }
            // 4 independent activation chains
            act2(LOP(a0[0]), LOP(a0[1]), LOP(a0[2]), LOP(a0[3]), ca[0], ha[0]);
            act2(HIP2(a0[0]), HIP2(a0[1]), HIP2(a0[2]), HIP2(a0[3]), cb[0], hb[0]);
            act2(LOP(a1[0]), LOP(a1[1]), LOP(a1[2]), LOP(a1[3]), ca[1], ha[1]);
            act2(HIP2(a1[0]), HIP2(a1[1]), HIP2(a1[2]), HIP2(a1[3]), cb[1], hb[1]);
            Bf[0] = make_bfrag(ha[0], hb[0]);
            Bf[1] = make_bfrag(ha[1], hb[1]);
        }

        // ---- FC head: dot(h, fc_w), reduce across 4 hi-lane groups ----
        #pragma unroll
        for (int m = 0; m < NTILES; ++m) {
            f32x2 s = ha[m] * fwa;
            s = __builtin_elementwise_fma(hb[m], fwb, s);
            float p = s[0] + s[1];
            p += __shfl_xor(p, 16, 64);
            p += __shfl_xor(p, 32, 64);
            if (hi == 0 && bidx[m] < nB) out[bidx[m]] = p + fb;
        }
    }
}

extern "C" void kernel_launch(void* const* d_in, const int* in_sizes, int n_in,
                              void* d_out, int out_size, void* d_ws, size_t ws_size,
                              hipStream_t stream) {
    const float* x     = (const float*)d_in[0];
    const float* W_ih0 = (const float*)d_in[1];
    const float* W_ih  = (const float*)d_in[2];
    const float* W_hh  = (const float*)d_in[3];
    const float* b_ih  = (const float*)d_in[4];
    const float* b_hh  = (const float*)d_in[5];
    const float* fc_w  = (const float*)d_in[6];
    const float* fc_b  = (const float*)d_in[7];
    float* out = (float*)d_out;

    const int B = in_sizes[0] / 14;
    lstm_mfma_kernel<<<NBLOCKS, THREADS, 0, stream>>>(
        x, W_ih0, W_ih, W_hh, b_ih, b_hh, fc_w, fc_b, out, B);
}

// Round 13
// 109.949 us; speedup vs baseline: 1.1326x; 1.0475x over previous
//
#include <hip/hip_runtime.h>

// LSTM_13451837571407 — R13: R12 minus the spill disaster.
// R12 postmortem: __launch_bounds__(1024,8) pinned VGPR=32 -> accumulator/
// prefetch state spilled to scratch (WRITE_SIZE 4->80MB, HBM 12% peak),
// +11µs. At 1024-thr blocks residency is thread-capped (2 blocks/CU) anyway;
// min-waves=8 bought nothing. R13 = identical code with (1024,2) like R9
// (40 VGPR, zero scratch), keeping the two real changes:
//  (1) both tiles' 4 MFMAs issued together (8-deep independent MFMA window),
//  (2) next group's x reg-prefetch during current group's 8 layers.
//
// Datapath (verified; absmax pinned at 2.441e-4 output-quant floor R2-R12):
//   layer 0: gates = x@W_ih0^T + (b_ih0+b_hh0)        (h=c=0, K padded 14->16)
//   layer l>=1: gates = h@(W_ih[l-1]+W_hh[l])^T + bc  (input==hidden quirk)
//   rows i,f,o scaled by -log2e (sigmoid=1/(1+exp2(y)));
//   rows g scaled by 2log2e (tanh=(exp2(y)-1)/(exp2(y)+1)).
//   W = fp16_hi + fp16_lo (22 bits), h = fp16 (cvt_pkrtz); one
//   v_mfma_f32_16x16x32_f16 with A=[Wh|Wl], B=[hf|hf] per gate-quadrant
//   (K32 = two stacked K16 frags, proven R7). Lane's D rows == its next-layer
//   B k-slots (zero cross-lane traffic).

typedef _Float16 f16x8 __attribute__((ext_vector_type(8)));
typedef _Float16 f16x2 __attribute__((ext_vector_type(2)));
typedef float f32x4 __attribute__((ext_vector_type(4)));
typedef float f32x2 __attribute__((ext_vector_type(2)));

#if __has_builtin(__builtin_amdgcn_mfma_f32_16x16x32_f16)
__device__ __forceinline__ f32x4 mfma32h(f16x8 a, f16x8 b, f32x4 c) {
    return __builtin_amdgcn_mfma_f32_16x16x32_f16(a, b, c, 0, 0, 0);
}
#else
__device__ __forceinline__ f32x4 mfma32h(f16x8 a, f16x8 b, f32x4 c) {
    asm volatile("v_mfma_f32_16x16x32_f16 %0, %1, %2, %0\n\ts_nop 7\n\ts_nop 7"
                 : "+v"(c) : "v"(a), "v"(b));
    return c;
}
#endif

#define NLOG2E  (-1.4426950408889634f)
#define G2LOG2E (2.8853900817779268f)
#define THREADS 1024
#define WAVES_PB (THREADS / 64)
#define NBLOCKS 512
#define NTILES 2

// LSTM nonlinearity on a pair of units (packed f32x2); rows pre-scaled.
__device__ __forceinline__ void act2(f32x2 yi, f32x2 yf, f32x2 yg, f32x2 yo,
                                     f32x2& c, f32x2& h) {
    f32x2 Ei, Ef, Eg, Eo;
    Ei[0] = __builtin_amdgcn_exp2f(yi[0]); Ei[1] = __builtin_amdgcn_exp2f(yi[1]);
    Ef[0] = __builtin_amdgcn_exp2f(yf[0]); Ef[1] = __builtin_amdgcn_exp2f(yf[1]);
    Eg[0] = __builtin_amdgcn_exp2f(yg[0]); Eg[1] = __builtin_amdgcn_exp2f(yg[1]);
    Eo[0] = __builtin_amdgcn_exp2f(yo[0]); Eo[1] = __builtin_amdgcn_exp2f(yo[1]);
    const f32x2 one = {1.f, 1.f};
    const f32x2 Di = Ei + one, Df = Ef + one, Do = Eo + one;
    const f32x2 P = __builtin_elementwise_fma(Di, Eg, Di);           // Di*(Eg+1)
    const f32x2 num = __builtin_elementwise_fma(
        Eg, Df, __builtin_elementwise_fma(c, P, -Df));               // (Eg-1)Df+cP
    const f32x2 DfP = Df * P;
    f32x2 R1;
    R1[0] = __builtin_amdgcn_rcpf(DfP[0]); R1[1] = __builtin_amdgcn_rcpf(DfP[1]);
    c = num * R1;
    const f32x2 cg = c * (f32x2){G2LOG2E, G2LOG2E};
    f32x2 Ec;
    Ec[0] = __builtin_amdgcn_exp2f(cg[0]); Ec[1] = __builtin_amdgcn_exp2f(cg[1]);
    const f32x2 Q = __builtin_elementwise_fma(Do, Ec, Do);           // Do*(Ec+1)
    f32x2 R2;
    R2[0] = __builtin_amdgcn_rcpf(Q[0]); R2[1] = __builtin_amdgcn_rcpf(Q[1]);
    h = __builtin_elementwise_fma(Ec, R2, -R2);                      // (Ec-1)/Q
}

#define LOP(v) __builtin_shufflevector(v, v, 0, 1)
#define HIP2(v) __builtin_shufflevector(v, v, 2, 3)

// duplicate-quad fp16 B fragment via packed RTZ converts: [h0..h3 | h0..h3]
__device__ __forceinline__ f16x8 make_bfrag(f32x2 ha, f32x2 hb) {
    const f16x2 p0 = __builtin_bit_cast(f16x2, __builtin_amdgcn_cvt_pkrtz(ha[0], ha[1]));
    const f16x2 p1 = __builtin_bit_cast(f16x2, __builtin_amdgcn_cvt_pkrtz(hb[0], hb[1]));
    return (f16x8){p0[0], p0[1], p1[0], p1[1], p0[0], p0[1], p1[0], p1[1]};
}

__global__ __launch_bounds__(THREADS, 2) void lstm_mfma_kernel(
    const float* __restrict__ x,      // [B][14]
    const float* __restrict__ W_ih0,  // [64][14]
    const float* __restrict__ W_ih,   // [7][64][16]
    const float* __restrict__ W_hh,   // [8][64][16]
    const float* __restrict__ b_ih,   // [8][64]
    const float* __restrict__ b_hh,   // [8][64]
    const float* __restrict__ fc_w,   // [16]
    const float* __restrict__ fc_b,   // [1]
    float* __restrict__ out,          // [B]
    int nB)
{
    // fragment-major: sWF[(l*4+t)*64 + lane] = 8 halfs [Wh0..3 | Wl0..3]
    __shared__ __align__(16) short sWF[8 * 4 * 64 * 8];  // 32 KB
    __shared__ __align__(16) float sB[8 * 64];
    __shared__ __align__(16) float sFC[20];

    const int tid = threadIdx.x;

    for (int slot = tid; slot < 2048; slot += THREADS) {
        const int l = slot >> 8;
        const int t = (slot >> 6) & 3;
        const int ln = slot & 63;
        const int row = t * 16 + (ln & 15);
        const int k0 = (ln >> 4) * 4;
        const float scale = (t == 2) ? G2LOG2E : NLOG2E;
        short frag[8];
        #pragma unroll
        for (int j = 0; j < 4; ++j) {
            const int k = k0 + j;
            float w;
            if (l == 0) w = (k < 14) ? W_ih0[row * 14 + k] : 0.0f;
            else        w = W_ih[(l - 1) * 1024 + row * 16 + k]
                          + W_hh[l * 1024 + row * 16 + k];
            w *= scale;
            const _Float16 wh = (_Float16)w;            // RNE fp16 hi
            const float wres = w - (float)wh;
            const _Float16 wl = (_Float16)wres;         // fp16 lo (22 bits total)
            frag[j]     = __builtin_bit_cast(short, wh);
            frag[4 + j] = __builtin_bit_cast(short, wl);
        }
        *(short4*)(sWF + slot * 8)     = make_short4(frag[0], frag[1], frag[2], frag[3]);
        *(short4*)(sWF + slot * 8 + 4) = make_short4(frag[4], frag[5], frag[6], frag[7]);
    }
    for (int idx = tid; idx < 512; idx += THREADS) {
        const int row = idx & 63;
        const float scale = ((row >> 4) == 2) ? G2LOG2E : NLOG2E;
        sB[idx] = (b_ih[idx] + b_hh[idx]) * scale;
    }
    if (tid < 16) sFC[tid] = fc_w[tid];
    if (tid == 16) sFC[16] = fc_b[0];
    __syncthreads();

    const int lane = tid & 63;
    const int wv = tid >> 6;
    const int bcol = lane & 15;   // batch within tile
    const int hi = lane >> 4;     // k-quad / D-row group

    const int n_grp = (nB + (16 * NTILES - 1)) / (16 * NTILES);
    const int waves_total = NBLOCKS * WAVES_PB;
    const int iters = (n_grp + waves_total - 1) / waves_total;
    const int gw = blockIdx.x * WAVES_PB + wv;
    const int grp_base = gw * iters;

    const short* wbase = sWF + (lane << 3);
    const float* bbase = sB + hi * 4;

    const f32x4 fw4 = *(const f32x4*)(sFC + hi * 4);
    const f32x2 fwa = LOP(fw4), fwb = HIP2(fw4);
    const float fb = sFC[16];

    // ---- register double-buffer for x ----
    int pf_b[NTILES];
    float2 pf_a[NTILES], pf_q[NTILES];
    auto prefetch = [&](int grp) {
        #pragma unroll
        for (int m = 0; m < NTILES; ++m) {
            const int b = grp * (16 * NTILES) + m * 16 + bcol;
            pf_b[m] = b;
            const int bc = b < nB ? b : nB - 1;
            const float* xr = x + bc * 14 + hi * 4;
            pf_a[m] = *(const float2*)xr;
            pf_q[m] = (hi < 3) ? *(const float2*)(xr + 2) : make_float2(0.f, 0.f);
        }
    };

    if (grp_base < n_grp) prefetch(grp_base);

    for (int it = 0; it < iters; ++it) {
        const int grp = grp_base + it;
        if (grp >= n_grp) break;

        // consume prefetched x
        int bidx[NTILES];
        f32x2 ha[NTILES], hb[NTILES];
        f16x8 Bf[NTILES];
        f32x2 ca[NTILES], cb[NTILES];
        #pragma unroll
        for (int m = 0; m < NTILES; ++m) {
            bidx[m] = pf_b[m];
            ha[m][0] = pf_a[m].x; ha[m][1] = pf_a[m].y;
            hb[m][0] = pf_q[m].x; hb[m][1] = pf_q[m].y;
            Bf[m] = make_bfrag(ha[m], hb[m]);
            ca[m] = (f32x2){0.f, 0.f};
            cb[m] = (f32x2){0.f, 0.f};
        }
        // issue next group's x loads; latency hides under 8 layers
        if (it + 1 < iters && grp + 1 < n_grp) prefetch(grp + 1);

        #pragma unroll
        for (int l = 0; l < 8; ++l) {
            // 8 independent MFMAs issued together (both tiles) — wide window
            f32x4 a0[4], a1[4];
            #pragma unroll
            for (int t = 0; t < 4; ++t) {
                const f16x8 fr = *(const f16x8*)(wbase + ((l * 4 + t) << 9));
                const f32x4 bias = *(const f32x4*)(bbase + l * 64 + t * 16);
                a0[t] = mfma32h(fr, Bf[0], bias);
                a1[t] = mfma32h(fr, Bf[1], bias);
            }
            // 4 independent activation chains
            act2(LOP(a0[0]), LOP(a0[1]), LOP(a0[2]), LOP(a0[3]), ca[0], ha[0]);
            act2(HIP2(a0[0]), HIP2(a0[1]), HIP2(a0[2]), HIP2(a0[3]), cb[0], hb[0]);
            act2(LOP(a1[0]), LOP(a1[1]), LOP(a1[2]), LOP(a1[3]), ca[1], ha[1]);
            act2(HIP2(a1[0]), HIP2(a1[1]), HIP2(a1[2]), HIP2(a1[3]), cb[1], hb[1]);
            Bf[0] = make_bfrag(ha[0], hb[0]);
            Bf[1] = make_bfrag(ha[1], hb[1]);
        }

        // ---- FC head: dot(h, fc_w), reduce across 4 hi-lane groups ----
        #pragma unroll
        for (int m = 0; m < NTILES; ++m) {
            f32x2 s = ha[m] * fwa;
            s = __builtin_elementwise_fma(hb[m], fwb, s);
            float p = s[0] + s[1];
            p += __shfl_xor(p, 16, 64);
            p += __shfl_xor(p, 32, 64);
            if (hi == 0 && bidx[m] < nB) out[bidx[m]] = p + fb;
        }
    }
}

extern "C" void kernel_launch(void* const* d_in, const int* in_sizes, int n_in,
                              void* d_out, int out_size, void* d_ws, size_t ws_size,
                              hipStream_t stream) {
    const float* x     = (const float*)d_in[0];
    const float* W_ih0 = (const float*)d_in[1];
    const float* W_ih  = (const float*)d_in[2];
    const float* W_hh  = (const float*)d_in[3];
    const float* b_ih  = (const float*)d_in[4];
    const float* b_hh  = (const float*)d_in[5];
    const float* fc_w  = (const float*)d_in[6];
    const float* fc_b  = (const float*)d_in[7];
    float* out = (float*)d_out;

    const int B = in_sizes[0] / 14;
    lstm_mfma_kernel<<<NBLOCKS, THREADS, 0, stream>>>(
        x, W_ih0, W_ih, W_hh, b_ih, b_hh, fc_w, fc_b, out, B);
}

// Round 14
// 107.932 us; speedup vs baseline: 1.1538x; 1.0187x over previous
//
#include <hip/hip_runtime.h>

// LSTM_13451837571407 — R14: R9 EXACT + x reg-prefetch only (single variable).
// R13 postmortem: {MFMA-hoist + prefetch} bundle regressed vs R9 (109.9 vs
// 103.9); hoist doubled acc live range (VGPR 40->44) and scheduled worse.
// R14 restores R9's per-tile MFMA->act order and adds ONLY the prefetch:
// next group's x (16B/lane) loads issue before the 8-layer compute, hiding
// ~600-900cy HBM latency that R9 exposed at each of 4 group starts.
//
// Datapath (verified; absmax pinned at 2.441e-4 output-quant floor R2-R13):
//   layer 0: gates = x@W_ih0^T + (b_ih0+b_hh0)        (h=c=0, K padded 14->16)
//   layer l>=1: gates = h@(W_ih[l-1]+W_hh[l])^T + bc  (input==hidden quirk)
//   rows i,f,o scaled by -log2e (sigmoid=1/(1+exp2(y)));
//   rows g scaled by 2log2e (tanh=(exp2(y)-1)/(exp2(y)+1)).
//   W = fp16_hi + fp16_lo (22 bits), h = fp16 (cvt_pkrtz); one
//   v_mfma_f32_16x16x32_f16 with A=[Wh|Wl], B=[hf|hf] per gate-quadrant
//   (K32 = two stacked K16 frags, proven R7). Lane's D rows == its next-layer
//   B k-slots (zero cross-lane traffic).

typedef _Float16 f16x8 __attribute__((ext_vector_type(8)));
typedef _Float16 f16x2 __attribute__((ext_vector_type(2)));
typedef float f32x4 __attribute__((ext_vector_type(4)));
typedef float f32x2 __attribute__((ext_vector_type(2)));

#if __has_builtin(__builtin_amdgcn_mfma_f32_16x16x32_f16)
__device__ __forceinline__ f32x4 mfma32h(f16x8 a, f16x8 b, f32x4 c) {
    return __builtin_amdgcn_mfma_f32_16x16x32_f16(a, b, c, 0, 0, 0);
}
#else
__device__ __forceinline__ f32x4 mfma32h(f16x8 a, f16x8 b, f32x4 c) {
    asm volatile("v_mfma_f32_16x16x32_f16 %0, %1, %2, %0\n\ts_nop 7\n\ts_nop 7"
                 : "+v"(c) : "v"(a), "v"(b));
    return c;
}
#endif

#define NLOG2E  (-1.4426950408889634f)
#define G2LOG2E (2.8853900817779268f)
#define THREADS 1024
#define WAVES_PB (THREADS / 64)
#define NBLOCKS 512
#define NTILES 2

// LSTM nonlinearity on a pair of units (packed f32x2); rows pre-scaled.
__device__ __forceinline__ void act2(f32x2 yi, f32x2 yf, f32x2 yg, f32x2 yo,
                                     f32x2& c, f32x2& h) {
    f32x2 Ei, Ef, Eg, Eo;
    Ei[0] = __builtin_amdgcn_exp2f(yi[0]); Ei[1] = __builtin_amdgcn_exp2f(yi[1]);
    Ef[0] = __builtin_amdgcn_exp2f(yf[0]); Ef[1] = __builtin_amdgcn_exp2f(yf[1]);
    Eg[0] = __builtin_amdgcn_exp2f(yg[0]); Eg[1] = __builtin_amdgcn_exp2f(yg[1]);
    Eo[0] = __builtin_amdgcn_exp2f(yo[0]); Eo[1] = __builtin_amdgcn_exp2f(yo[1]);
    const f32x2 one = {1.f, 1.f};
    const f32x2 Di = Ei + one, Df = Ef + one, Do = Eo + one;
    const f32x2 P = __builtin_elementwise_fma(Di, Eg, Di);           // Di*(Eg+1)
    const f32x2 num = __builtin_elementwise_fma(
        Eg, Df, __builtin_elementwise_fma(c, P, -Df));               // (Eg-1)Df+cP
    const f32x2 DfP = Df * P;
    f32x2 R1;
    R1[0] = __builtin_amdgcn_rcpf(DfP[0]); R1[1] = __builtin_amdgcn_rcpf(DfP[1]);
    c = num * R1;
    const f32x2 cg = c * (f32x2){G2LOG2E, G2LOG2E};
    f32x2 Ec;
    Ec[0] = __builtin_amdgcn_exp2f(cg[0]); Ec[1] = __builtin_amdgcn_exp2f(cg[1]);
    const f32x2 Q = __builtin_elementwise_fma(Do, Ec, Do);           // Do*(Ec+1)
    f32x2 R2;
    R2[0] = __builtin_amdgcn_rcpf(Q[0]); R2[1] = __builtin_amdgcn_rcpf(Q[1]);
    h = __builtin_elementwise_fma(Ec, R2, -R2);                      // (Ec-1)/Q
}

#define LOP(v) __builtin_shufflevector(v, v, 0, 1)
#define HIP2(v) __builtin_shufflevector(v, v, 2, 3)

// duplicate-quad fp16 B fragment via packed RTZ converts: [h0..h3 | h0..h3]
__device__ __forceinline__ f16x8 make_bfrag(f32x2 ha, f32x2 hb) {
    const f16x2 p0 = __builtin_bit_cast(f16x2, __builtin_amdgcn_cvt_pkrtz(ha[0], ha[1]));
    const f16x2 p1 = __builtin_bit_cast(f16x2, __builtin_amdgcn_cvt_pkrtz(hb[0], hb[1]));
    return (f16x8){p0[0], p0[1], p1[0], p1[1], p0[0], p0[1], p1[0], p1[1]};
}

__global__ __launch_bounds__(THREADS, 2) void lstm_mfma_kernel(
    const float* __restrict__ x,      // [B][14]
    const float* __restrict__ W_ih0,  // [64][14]
    const float* __restrict__ W_ih,   // [7][64][16]
    const float* __restrict__ W_hh,   // [8][64][16]
    const float* __restrict__ b_ih,   // [8][64]
    const float* __restrict__ b_hh,   // [8][64]
    const float* __restrict__ fc_w,   // [16]
    const float* __restrict__ fc_b,   // [1]
    float* __restrict__ out,          // [B]
    int nB)
{
    // fragment-major: sWF[(l*4+t)*64 + lane] = 8 halfs [Wh0..3 | Wl0..3]
    __shared__ __align__(16) short sWF[8 * 4 * 64 * 8];  // 32 KB
    __shared__ __align__(16) float sB[8 * 64];
    __shared__ __align__(16) float sFC[20];

    const int tid = threadIdx.x;

    for (int slot = tid; slot < 2048; slot += THREADS) {
        const int l = slot >> 8;
        const int t = (slot >> 6) & 3;
        const int ln = slot & 63;
        const int row = t * 16 + (ln & 15);
        const int k0 = (ln >> 4) * 4;
        const float scale = (t == 2) ? G2LOG2E : NLOG2E;
        short frag[8];
        #pragma unroll
        for (int j = 0; j < 4; ++j) {
            const int k = k0 + j;
            float w;
            if (l == 0) w = (k < 14) ? W_ih0[row * 14 + k] : 0.0f;
            else        w = W_ih[(l - 1) * 1024 + row * 16 + k]
                          + W_hh[l * 1024 + row * 16 + k];
            w *= scale;
            const _Float16 wh = (_Float16)w;            // RNE fp16 hi
            const float wres = w - (float)wh;
            const _Float16 wl = (_Float16)wres;         // fp16 lo (22 bits total)
            frag[j]     = __builtin_bit_cast(short, wh);
            frag[4 + j] = __builtin_bit_cast(short, wl);
        }
        *(short4*)(sWF + slot * 8)     = make_short4(frag[0], frag[1], frag[2], frag[3]);
        *(short4*)(sWF + slot * 8 + 4) = make_short4(frag[4], frag[5], frag[6], frag[7]);
    }
    for (int idx = tid; idx < 512; idx += THREADS) {
        const int row = idx & 63;
        const float scale = ((row >> 4) == 2) ? G2LOG2E : NLOG2E;
        sB[idx] = (b_ih[idx] + b_hh[idx]) * scale;
    }
    if (tid < 16) sFC[tid] = fc_w[tid];
    if (tid == 16) sFC[16] = fc_b[0];
    __syncthreads();

    const int lane = tid & 63;
    const int wv = tid >> 6;
    const int bcol = lane & 15;   // batch within tile
    const int hi = lane >> 4;     // k-quad / D-row group

    const int n_grp = (nB + (16 * NTILES - 1)) / (16 * NTILES);
    const int waves_total = NBLOCKS * WAVES_PB;
    const int iters = (n_grp + waves_total - 1) / waves_total;
    const int gw = blockIdx.x * WAVES_PB + wv;
    const int grp_base = gw * iters;

    const short* wbase = sWF + (lane << 3);
    const float* bbase = sB + hi * 4;

    const f32x4 fw4 = *(const f32x4*)(sFC + hi * 4);
    const f32x2 fwa = LOP(fw4), fwb = HIP2(fw4);
    const float fb = sFC[16];

    // ---- register double-buffer for x ----
    int pf_b[NTILES];
    float2 pf_a[NTILES], pf_q[NTILES];
    auto prefetch = [&](int grp) {
        #pragma unroll
        for (int m = 0; m < NTILES; ++m) {
            const int b = grp * (16 * NTILES) + m * 16 + bcol;
            pf_b[m] = b;
            const int bc = b < nB ? b : nB - 1;
            const float* xr = x + bc * 14 + hi * 4;
            pf_a[m] = *(const float2*)xr;
            pf_q[m] = (hi < 3) ? *(const float2*)(xr + 2) : make_float2(0.f, 0.f);
        }
    };

    if (grp_base < n_grp) prefetch(grp_base);

    for (int it = 0; it < iters; ++it) {
        const int grp = grp_base + it;
        if (grp >= n_grp) break;

        // consume prefetched x
        int bidx[NTILES];
        f32x2 ha[NTILES], hb[NTILES];
        f16x8 Bf[NTILES];
        f32x2 ca[NTILES], cb[NTILES];
        #pragma unroll
        for (int m = 0; m < NTILES; ++m) {
            bidx[m] = pf_b[m];
            ha[m][0] = pf_a[m].x; ha[m][1] = pf_a[m].y;
            hb[m][0] = pf_q[m].x; hb[m][1] = pf_q[m].y;
            Bf[m] = make_bfrag(ha[m], hb[m]);
            ca[m] = (f32x2){0.f, 0.f};
            cb[m] = (f32x2){0.f, 0.f};
        }
        // issue next group's x loads; latency hides under 8 layers of compute
        if (it + 1 < iters && grp + 1 < n_grp) prefetch(grp + 1);

        #pragma unroll
        for (int l = 0; l < 8; ++l) {
            // R9 order: per-tile MFMA block then its activation (short acc
            // live range; tile m+1's MFMAs overlap tile m's trans chain)
            f16x8 fr[4];
            f32x4 bias[4];
            #pragma unroll
            for (int t = 0; t < 4; ++t) {
                fr[t] = *(const f16x8*)(wbase + ((l * 4 + t) << 9));
                bias[t] = *(const f32x4*)(bbase + l * 64 + t * 16);
            }
            #pragma unroll
            for (int m = 0; m < NTILES; ++m) {
                f32x4 a[4];
                #pragma unroll
                for (int t = 0; t < 4; ++t) {
                    a[t] = mfma32h(fr[t], Bf[m], bias[t]);
                }
                act2(LOP(a[0]), LOP(a[1]), LOP(a[2]), LOP(a[3]), ca[m], ha[m]);
                act2(HIP2(a[0]), HIP2(a[1]), HIP2(a[2]), HIP2(a[3]), cb[m], hb[m]);
                Bf[m] = make_bfrag(ha[m], hb[m]);
            }
        }

        // ---- FC head: dot(h, fc_w), reduce across 4 hi-lane groups ----
        #pragma unroll
        for (int m = 0; m < NTILES; ++m) {
            f32x2 s = ha[m] * fwa;
            s = __builtin_elementwise_fma(hb[m], fwb, s);
            float p = s[0] + s[1];
            p += __shfl_xor(p, 16, 64);
            p += __shfl_xor(p, 32, 64);
            if (hi == 0 && bidx[m] < nB) out[bidx[m]] = p + fb;
        }
    }
}

extern "C" void kernel_launch(void* const* d_in, const int* in_sizes, int n_in,
                              void* d_out, int out_size, void* d_ws, size_t ws_size,
                              hipStream_t stream) {
    const float* x     = (const float*)d_in[0];
    const float* W_ih0 = (const float*)d_in[1];
    const float* W_ih  = (const float*)d_in[2];
    const float* W_hh  = (const float*)d_in[3];
    const float* b_ih  = (const float*)d_in[4];
    const float* b_hh  = (const float*)d_in[5];
    const float* fc_w  = (const float*)d_in[6];
    const float* fc_b  = (const float*)d_in[7];
    float* out = (float*)d_out;

    const int B = in_sizes[0] / 14;
    lstm_mfma_kernel<<<NBLOCKS, THREADS, 0, stream>>>(
        x, W_ih0, W_ih, W_hh, b_ih, b_hh, fc_w, fc_b, out, B);
}